// Round 2
// baseline (1009.743 us; speedup 1.0000x reference)
//
#include <hip/hip_runtime.h>

#define DM 256
#define DI 512
#define NL 10

__device__ __forceinline__ float dot4(float4 a, float4 b) {
    return a.x*b.x + a.y*b.y + a.z*b.z + a.w*b.w;
}
__device__ __forceinline__ float silu(float x) {
    return x / (1.f + __expf(-x));
}

// ---------------- Kernel 1: spatial mean pool of x1..x4 -> pooled (4,40,256)
__global__ void pool_kernel(const float* __restrict__ x1, const float* __restrict__ x2,
                            const float* __restrict__ x3, const float* __restrict__ x4,
                            float* __restrict__ pooled)
{
    int wid  = (blockIdx.x * blockDim.x + threadIdx.x) >> 6;   // one wave per row
    int lane = threadIdx.x & 63;
    if (wid >= 40960) return;
    int img = wid / 10240;
    int r   = wid % 10240;          // bt*256 + c
    const float* src; int hw;
    if      (img == 0) { src = x1; hw = 3136; }
    else if (img == 1) { src = x2; hw = 784; }
    else if (img == 2) { src = x3; hw = 196; }
    else               { src = x4; hw = 49; }
    const float* row = src + (size_t)r * hw;
    float s = 0.f;
    if (hw == 49) {
        if (lane < 49) s = row[lane];
    } else {
        int n4 = hw >> 2;
        for (int j = lane; j < n4; j += 64) {
            float4 v = *(const float4*)(row + j*4);
            s += v.x + v.y + v.z + v.w;
        }
    }
    #pragma unroll
    for (int off = 32; off; off >>= 1) s += __shfl_down(s, off);
    if (lane == 0) pooled[img*10240 + r] = s / (float)hw;
}

// ---------------- Kernel 2: the 8 Mamba encoders (one block per (e,b))
__global__ __launch_bounds__(1024)
void encoder_kernel(const float* __restrict__ audio,
                    const float* __restrict__ vis_w, const float* __restrict__ vis_b,
                    const float* __restrict__ ln_g,  const float* __restrict__ ln_b,
                    const float* __restrict__ in_w,  const float* __restrict__ conv_w,
                    const float* __restrict__ conv_b,const float* __restrict__ xp_w,
                    const float* __restrict__ dt_w,  const float* __restrict__ dt_b,
                    const float* __restrict__ A_log, const float* __restrict__ Dp,
                    const float* __restrict__ out_w, const float* __restrict__ gate_w,
                    const float* __restrict__ gate_b,
                    const float* __restrict__ pooled, float* __restrict__ gates)
{
    __shared__ float sx [NL*DM];   // carry (2560)
    __shared__ float sh [NL*DM];   // LN output (2560)
    __shared__ float sxi[NL*DI];   // xi (5120)
    __shared__ float sxc[NL*DI];   // xc -> y2 (5120)
    __shared__ float sdbl[NL*48];  // dt|B|C (480)

    const int tid = threadIdx.x;
    const int e = blockIdx.x >> 2;
    const int b = blockIdx.x & 3;

    // ---- build input x (10x256) into sx
    if (e < 4) {
        for (int i = tid; i < NL*DM; i += 1024) sx[i] = audio[b*(NL*DM) + i];
    } else {
        const int img = e - 4;
        for (int i = tid; i < NL*DM; i += 1024) sxi[i] = pooled[img*10240 + b*(NL*DM) + i];
        __syncthreads();
        int c = tid & 255, q = tid >> 8;
        const float* w = vis_w + img*65536 + c*256;
        for (int l = q; l < NL; l += 4) {
            float acc = vis_b[img*256 + c];
            for (int k4 = 0; k4 < 64; k4++) {
                float4 wv = *(const float4*)(w + k4*4);
                float4 xv = *(const float4*)(&sxi[l*DM + k4*4]);
                acc += dot4(wv, xv);
            }
            sx[l*DM + c] = acc;
        }
    }
    __syncthreads();

    float zreg[NL];   // z kept in registers (threads tid<512 own channel d=tid)

    for (int layer = 0; layer < 3; layer++) {
        const int el = e*3 + layer;

        // ---- LayerNorm: wave w handles row l=w
        {
            int wv = tid >> 6, lane = tid & 63;
            if (wv < NL) {
                int l = wv;
                float v[4], s = 0.f, ss = 0.f;
                #pragma unroll
                for (int k = 0; k < 4; k++) {
                    v[k] = sx[l*DM + lane + 64*k];
                    s += v[k]; ss += v[k]*v[k];
                }
                #pragma unroll
                for (int off = 32; off; off >>= 1) {
                    s  += __shfl_xor(s, off);
                    ss += __shfl_xor(ss, off);
                }
                float m   = s  * (1.f/256.f);
                float var = ss * (1.f/256.f) - m*m;
                float rs  = rsqrtf(var + 1e-5f);
                #pragma unroll
                for (int k = 0; k < 4; k++) {
                    int c = lane + 64*k;
                    sh[l*DM + c] = (v[k]-m)*rs*ln_g[el*256 + c] + ln_b[el*256 + c];
                }
            }
        }
        __syncthreads();

        // ---- xz GEMM: thread t<512 computes columns t (xi) and t+512 (z)
        if (tid < 512) {
            float a0[NL], a1[NL];
            #pragma unroll
            for (int l = 0; l < NL; l++) { a0[l] = 0.f; a1[l] = 0.f; }
            const float* w0 = in_w + el*262144 + tid*256;
            const float* w1 = w0 + 131072;
            for (int c4 = 0; c4 < 64; c4++) {
                float4 wa = *(const float4*)(w0 + c4*4);
                float4 wb = *(const float4*)(w1 + c4*4);
                #pragma unroll
                for (int l = 0; l < NL; l++) {
                    float4 s4 = *(const float4*)(&sh[l*DM + c4*4]);
                    a0[l] += dot4(s4, wa);
                    a1[l] += dot4(s4, wb);
                }
            }
            #pragma unroll
            for (int l = 0; l < NL; l++) { sxi[l*DI + tid] = a0[l]; zreg[l] = a1[l]; }
        }
        __syncthreads();

        // ---- causal depthwise conv (k=4) + silu -> sxc
        {
            int d = tid & 511, lg = tid >> 9;
            float4 cw = *(const float4*)(conv_w + el*2048 + d*4);
            float cb  = conv_b[el*512 + d];
            #pragma unroll
            for (int i = 0; i < 5; i++) {
                int l = lg*5 + i;
                float acc = cb + sxi[l*DI + d]*cw.w;
                if (l >= 1) acc += sxi[(l-1)*DI + d]*cw.z;
                if (l >= 2) acc += sxi[(l-2)*DI + d]*cw.y;
                if (l >= 3) acc += sxi[(l-3)*DI + d]*cw.x;
                sxc[l*DI + d] = silu(acc);
            }
        }
        __syncthreads();

        // ---- dbl GEMM: (10,48) = xc @ xp_w.T
        if (tid < 480) {
            int r = tid % 48, l = tid / 48;
            const float* w = xp_w + el*24576 + r*512;
            float acc = 0.f;
            for (int d4 = 0; d4 < 128; d4++) {
                float4 wv = *(const float4*)(w + d4*4);
                float4 xv = *(const float4*)(&sxc[l*DI + d4*4]);
                acc += dot4(wv, xv);
            }
            sdbl[l*48 + r] = acc;
        }
        __syncthreads();

        // ---- fused delta -> scan -> (y + xc*Dp)*silu(z): thread d=tid<512
        if (tid < 512) {
            const int d = tid;
            const float* dwp = dt_w + el*8192 + d*16;
            float4 dw0 = *(const float4*)(dwp);
            float4 dw1 = *(const float4*)(dwp + 4);
            float4 dw2 = *(const float4*)(dwp + 8);
            float4 dw3 = *(const float4*)(dwp + 12);
            float dbv = dt_b[el*512 + d];
            float Dpv = Dp[el*512 + d];
            float Av[16];
            #pragma unroll
            for (int n = 0; n < 16; n++) Av[n] = -__expf(A_log[el*8192 + d*16 + n]);
            float h[16];
            #pragma unroll
            for (int n = 0; n < 16; n++) h[n] = 0.f;
            #pragma unroll
            for (int l = 0; l < NL; l++) {
                float4 t0 = *(const float4*)(&sdbl[l*48]);
                float4 t1 = *(const float4*)(&sdbl[l*48 + 4]);
                float4 t2 = *(const float4*)(&sdbl[l*48 + 8]);
                float4 t3 = *(const float4*)(&sdbl[l*48 + 12]);
                float acc = dbv + dot4(t0,dw0) + dot4(t1,dw1) + dot4(t2,dw2) + dot4(t3,dw3);
                float dl = fmaxf(acc, 0.f) + log1pf(__expf(-fabsf(acc)));  // softplus
                float xcv = sxc[l*DI + d];
                float du  = dl * xcv;
                float y = 0.f;
                #pragma unroll
                for (int n = 0; n < 16; n++) {
                    float Bn = sdbl[l*48 + 16 + n];
                    float Cn = sdbl[l*48 + 32 + n];
                    h[n] = __expf(dl*Av[n])*h[n] + du*Bn;
                    y += h[n]*Cn;
                }
                float zv = zreg[l];
                sxc[l*DI + d] = (y + xcv*Dpv) * silu(zv);
            }
        }
        __syncthreads();

        // ---- out GEMM + residual: sx = sh + y2 @ out_w.T   (residual is on LN OUTPUT!)
        {
            int o = tid & 255, q = tid >> 8;
            const float* w = out_w + el*131072 + o*512;
            for (int l = q; l < NL; l += 4) {
                float acc = 0.f;
                for (int d4 = 0; d4 < 128; d4++) {
                    float4 wv = *(const float4*)(w + d4*4);
                    float4 yv = *(const float4*)(&sxc[l*DI + d4*4]);
                    acc += dot4(wv, yv);
                }
                sx[l*DM + o] = sh[l*DM + o] + acc;
            }
        }
        __syncthreads();
    }

    // ---- gate GEMM + silu -> gates[e][b][l][o]
    {
        int o = tid & 255, q = tid >> 8;
        const float* w = gate_w + e*65536 + o*256;
        float gb = gate_b[e*256 + o];
        for (int l = q; l < NL; l += 4) {
            float acc = gb;
            for (int d4 = 0; d4 < 64; d4++) {
                float4 wv = *(const float4*)(w + d4*4);
                float4 xv = *(const float4*)(&sx[l*DM + d4*4]);
                acc += dot4(wv, xv);
            }
            gates[(e*40 + b*10 + l)*256 + o] = silu(acc);
        }
    }
}

// ---------------- Kernel 3: x_out = x * (1 + gate)
__global__ void scale_kernel(const float* __restrict__ x1, const float* __restrict__ x2,
                             const float* __restrict__ x3, const float* __restrict__ x4,
                             const float* __restrict__ gates, float* __restrict__ out)
{
    int wid  = (blockIdx.x * blockDim.x + threadIdx.x) >> 6;
    int lane = threadIdx.x & 63;
    if (wid >= 40960) return;
    int t = wid / 10240, r = wid % 10240;
    int bt = r >> 8, c = r & 255;
    int lb = (bt & 3)*10 + (bt >> 2);     // (l,b)-transposed gate index
    const float* src; int hw; size_t obase; int gidx;
    if      (t == 0) { src = x4; hw = 49;   obase = 0;        gidx = (120 + lb)*256 + c; }
    else if (t == 1) { src = x3; hw = 196;  obase = 501760;   gidx = ( 80 + lb)*256 + c; }
    else if (t == 2) { src = x2; hw = 784;  obase = 2508800;  gidx = ( 40 + lb)*256 + c; }
    else             { src = x1; hw = 3136; obase = 10536960; gidx = r; }  // e=0: (b,l) order
    float scale = 1.f + gates[gidx];
    const float* row = src + (size_t)r * hw;
    float* orow = out + obase + (size_t)r * hw;
    if (hw == 49) {
        if (lane < 49) orow[lane] = row[lane] * scale;
    } else {
        int n4 = hw >> 2;
        for (int j = lane; j < n4; j += 64) {
            float4 v = *(const float4*)(row + j*4);
            v.x *= scale; v.y *= scale; v.z *= scale; v.w *= scale;
            *(float4*)(orow + j*4) = v;
        }
    }
}

// ---------------- Kernel 4: ao = audio * (1 + mean(vis gates))
__global__ void ao_kernel(const float* __restrict__ audio, const float* __restrict__ gates,
                          float* __restrict__ out)
{
    int i = blockIdx.x * blockDim.x + threadIdx.x;
    if (i >= 10240) return;
    int bt = i >> 8, c = i & 255;
    int lb = (bt & 3)*10 + (bt >> 2);
    float vg = 0.25f * (gates[(160 + lb)*256 + c] + gates[(200 + lb)*256 + c] +
                        gates[(240 + lb)*256 + c] + gates[(280 + lb)*256 + c]);
    out[42649600 + i] = audio[i] * (1.f + vg);
}

extern "C" void kernel_launch(void* const* d_in, const int* in_sizes, int n_in,
                              void* d_out, int out_size, void* d_ws, size_t ws_size,
                              hipStream_t stream)
{
    const float* x1     = (const float*)d_in[0];
    const float* x2     = (const float*)d_in[1];
    const float* x3     = (const float*)d_in[2];
    const float* x4     = (const float*)d_in[3];
    const float* audio  = (const float*)d_in[4];
    const float* vis_w  = (const float*)d_in[5];
    const float* vis_b  = (const float*)d_in[6];
    const float* ln_g   = (const float*)d_in[7];
    const float* ln_b   = (const float*)d_in[8];
    const float* in_w   = (const float*)d_in[9];
    const float* conv_w = (const float*)d_in[10];
    const float* conv_b = (const float*)d_in[11];
    const float* xp_w   = (const float*)d_in[12];
    const float* dt_w   = (const float*)d_in[13];
    const float* dt_b   = (const float*)d_in[14];
    const float* A_log  = (const float*)d_in[15];
    const float* Dp     = (const float*)d_in[16];
    const float* out_w  = (const float*)d_in[17];
    const float* gate_w = (const float*)d_in[18];
    const float* gate_b = (const float*)d_in[19];

    float* pooled = (float*)d_ws;            // 4*40*256 = 40960 floats
    float* gates  = pooled + 40960;          // 8*4*10*256 = 81920 floats
    float* out    = (float*)d_out;

    pool_kernel<<<dim3(40960/4), dim3(256), 0, stream>>>(x1, x2, x3, x4, pooled);
    encoder_kernel<<<dim3(32), dim3(1024), 0, stream>>>(audio, vis_w, vis_b, ln_g, ln_b,
        in_w, conv_w, conv_b, xp_w, dt_w, dt_b, A_log, Dp, out_w, gate_w, gate_b,
        pooled, gates);
    scale_kernel<<<dim3(40960/4), dim3(256), 0, stream>>>(x1, x2, x3, x4, gates, out);
    ao_kernel<<<dim3(10), dim3(1024), 0, stream>>>(audio, gates, out);
}

// Round 3
// 530.890 us; speedup vs baseline: 1.9020x; 1.9020x over previous
//
#include <hip/hip_runtime.h>

#define DM 256
#define DI 512
#define NL 10

__device__ __forceinline__ float dot4(float4 a, float4 b) {
    return a.x*b.x + a.y*b.y + a.z*b.z + a.w*b.w;
}
__device__ __forceinline__ float silu(float x) {
    return x / (1.f + __expf(-x));
}

// ws layout (floats)
#define WS_POOLED 0
#define WS_GATES  40960
#define WS_SX     122880
#define WS_SH     204800
#define WS_XI     286720
#define WS_ZB     450560
#define WS_Y2     614400

// ---------------- Kernel 1: spatial mean pool of x1..x4 -> pooled (4,40,256)
__global__ void pool_kernel(const float* __restrict__ x1, const float* __restrict__ x2,
                            const float* __restrict__ x3, const float* __restrict__ x4,
                            float* __restrict__ pooled)
{
    int wid  = (blockIdx.x * blockDim.x + threadIdx.x) >> 6;
    int lane = threadIdx.x & 63;
    if (wid >= 40960) return;
    int img = wid / 10240;
    int r   = wid % 10240;
    const float* src; int hw;
    if      (img == 0) { src = x1; hw = 3136; }
    else if (img == 1) { src = x2; hw = 784; }
    else if (img == 2) { src = x3; hw = 196; }
    else               { src = x4; hw = 49; }
    const float* row = src + (size_t)r * hw;
    float s = 0.f;
    if (hw == 49) {
        if (lane < 49) s = row[lane];
    } else {
        int n4 = hw >> 2;
        for (int j = lane; j < n4; j += 64) {
            float4 v = *(const float4*)(row + j*4);
            s += v.x + v.y + v.z + v.w;
        }
    }
    #pragma unroll
    for (int off = 32; off; off >>= 1) s += __shfl_down(s, off);
    if (lane == 0) pooled[img*10240 + r] = s / (float)hw;
}

// ---------------- Kernel 2: build encoder input sx (32 blocks = (e,b), 256 thr)
__global__ __launch_bounds__(256)
void build_kernel(const float* __restrict__ audio, const float* __restrict__ vis_w,
                  const float* __restrict__ vis_b, const float* __restrict__ ws)
{
    __shared__ float px[NL*DM];
    const int tid = threadIdx.x;
    const int e = blockIdx.x >> 2, b = blockIdx.x & 3;
    float* sx = (float*)ws + WS_SX + (e*4 + b)*NL*DM;
    if (e < 4) {
        for (int i = tid; i < NL*DM; i += 256) sx[i] = audio[b*NL*DM + i];
        return;
    }
    const int img = e - 4;
    for (int i = tid; i < NL*DM; i += 256) px[i] = ((const float*)ws)[WS_POOLED + img*10240 + b*NL*DM + i];
    __syncthreads();
    const int c = tid;
    const float* w = vis_w + img*65536 + c*256;
    float bias = vis_b[img*256 + c];
    float acc[NL];
    #pragma unroll
    for (int l = 0; l < NL; l++) acc[l] = bias;
    for (int k4 = 0; k4 < 64; k4++) {
        float4 wv = *(const float4*)(w + k4*4);
        #pragma unroll
        for (int l = 0; l < NL; l++)
            acc[l] += dot4(wv, *(const float4*)(&px[l*DM + k4*4]));
    }
    #pragma unroll
    for (int l = 0; l < NL; l++) sx[l*DM + c] = acc[l];
}

// ---------------- Kernel 3: LN + xz GEMM.  grid = 8e*16chunks, 256 thr.
// thread: col r = chunk*64 + (t&63) of in_w[el] (r<512 -> xi, else z), b = t>>6
__global__ __launch_bounds__(256)
void lnxz_kernel(const float* __restrict__ ln_g, const float* __restrict__ ln_b,
                 const float* __restrict__ in_w, float* __restrict__ ws, int layer)
{
    __shared__ float sh_l[4*NL*DM];   // 40 KB: LN output, rows (b*10+l)
    const int tid = threadIdx.x;
    const int e = blockIdx.x >> 4, chunk = blockIdx.x & 15;
    const int el = e*3 + layer;
    const int lane = tid & 63, b = tid >> 6;   // wave w handles batch b=w

    const float* sx = ws + WS_SX + (e*4 + b)*NL*DM;
    float* sh_g = ws + WS_SH + (e*4 + b)*NL*DM;

    for (int l = 0; l < NL; l++) {
        float v[4], s = 0.f, ss = 0.f;
        #pragma unroll
        for (int k = 0; k < 4; k++) {
            v[k] = sx[l*DM + lane + 64*k];
            s += v[k]; ss += v[k]*v[k];
        }
        #pragma unroll
        for (int off = 32; off; off >>= 1) { s += __shfl_xor(s, off); ss += __shfl_xor(ss, off); }
        float m = s * (1.f/256.f);
        float rs = rsqrtf(ss * (1.f/256.f) - m*m + 1e-5f);
        #pragma unroll
        for (int k = 0; k < 4; k++) {
            int c = lane + 64*k;
            float hv = (v[k]-m)*rs*ln_g[el*256 + c] + ln_b[el*256 + c];
            sh_l[(b*NL + l)*DM + c] = hv;
            if (chunk == 0) sh_g[l*DM + c] = hv;
        }
    }
    __syncthreads();

    const int r = chunk*64 + lane;
    const float* w = in_w + (size_t)el*262144 + (size_t)r*256;
    float acc[NL];
    #pragma unroll
    for (int l = 0; l < NL; l++) acc[l] = 0.f;
    for (int k4 = 0; k4 < 64; k4++) {
        float4 wv = *(const float4*)(w + k4*4);
        #pragma unroll
        for (int l = 0; l < NL; l++)
            acc[l] += dot4(wv, *(const float4*)(&sh_l[(b*NL + l)*DM + k4*4]));
    }
    float* dst = (r < 512) ? (ws + WS_XI + (e*4 + b)*NL*DI + r)
                           : (ws + WS_ZB + (e*4 + b)*NL*DI + (r - 512));
    #pragma unroll
    for (int l = 0; l < NL; l++) dst[l*DI] = acc[l];
}

// ---------------- Kernel 4: conv+silu -> dbl GEMM -> softplus -> scan -> y2.
// grid = 32 (e,b), 512 thr
__global__ __launch_bounds__(512)
void mid_kernel(const float* __restrict__ conv_w, const float* __restrict__ conv_b,
                const float* __restrict__ xp_w,   const float* __restrict__ dt_w,
                const float* __restrict__ dt_b,   const float* __restrict__ A_log,
                const float* __restrict__ Dp,     float* __restrict__ ws, int layer)
{
    __shared__ float xi_l[NL*DI];
    __shared__ float xc_l[NL*DI];
    __shared__ float dbl_l[NL*48];
    const int tid = threadIdx.x;
    const int e = blockIdx.x >> 2, b = blockIdx.x & 3;
    const int el = e*3 + layer;
    const float* xi = ws + WS_XI + (e*4 + b)*NL*DI;
    const float* zb = ws + WS_ZB + (e*4 + b)*NL*DI;
    float* y2 = ws + WS_Y2 + (e*4 + b)*NL*DI;

    for (int i = tid; i < NL*DI; i += 512) xi_l[i] = xi[i];
    __syncthreads();

    // conv + silu
    {
        const int d = tid;
        float4 cw = *(const float4*)(conv_w + el*2048 + d*4);
        float cb  = conv_b[el*512 + d];
        #pragma unroll
        for (int l = 0; l < NL; l++) {
            float acc = cb + xi_l[l*DI + d]*cw.w;
            if (l >= 1) acc += xi_l[(l-1)*DI + d]*cw.z;
            if (l >= 2) acc += xi_l[(l-2)*DI + d]*cw.y;
            if (l >= 3) acc += xi_l[(l-3)*DI + d]*cw.x;
            xc_l[l*DI + d] = silu(acc);
        }
    }
    __syncthreads();

    // dbl GEMM (10,48)
    if (tid < 480) {
        int r = tid % 48, l = tid / 48;
        const float* w = xp_w + el*24576 + r*512;
        float acc = 0.f;
        for (int d4 = 0; d4 < 128; d4++)
            acc += dot4(*(const float4*)(w + d4*4), *(const float4*)(&xc_l[l*DI + d4*4]));
        dbl_l[l*48 + r] = acc;
    }
    __syncthreads();

    // delta -> scan -> y2
    {
        const int d = tid;
        const float* dwp = dt_w + el*8192 + d*16;
        float4 dw0 = *(const float4*)(dwp);
        float4 dw1 = *(const float4*)(dwp + 4);
        float4 dw2 = *(const float4*)(dwp + 8);
        float4 dw3 = *(const float4*)(dwp + 12);
        float dbv = dt_b[el*512 + d];
        float Dpv = Dp[el*512 + d];
        float Av[16];
        #pragma unroll
        for (int n = 0; n < 16; n++) Av[n] = -__expf(A_log[el*8192 + d*16 + n]);
        float h[16];
        #pragma unroll
        for (int n = 0; n < 16; n++) h[n] = 0.f;
        #pragma unroll
        for (int l = 0; l < NL; l++) {
            float4 t0 = *(const float4*)(&dbl_l[l*48]);
            float4 t1 = *(const float4*)(&dbl_l[l*48 + 4]);
            float4 t2 = *(const float4*)(&dbl_l[l*48 + 8]);
            float4 t3 = *(const float4*)(&dbl_l[l*48 + 12]);
            float acc = dbv + dot4(t0,dw0) + dot4(t1,dw1) + dot4(t2,dw2) + dot4(t3,dw3);
            float dl = fmaxf(acc, 0.f) + log1pf(__expf(-fabsf(acc)));
            float xcv = xc_l[l*DI + d];
            float du  = dl * xcv;
            float y = 0.f;
            #pragma unroll
            for (int n = 0; n < 16; n++) {
                float Bn = dbl_l[l*48 + 16 + n];
                float Cn = dbl_l[l*48 + 32 + n];
                h[n] = __expf(dl*Av[n])*h[n] + du*Bn;
                y += h[n]*Cn;
            }
            y2[l*DI + d] = (y + xcv*Dpv) * silu(zb[l*DI + d]);
        }
    }
}

// ---------------- Kernel 5: out GEMM + residual (sx = sh + y2 @ out_w.T)
// grid = 8e*4chunks, 256 thr; thread: o = chunk*64 + (t&63), b = t>>6
__global__ __launch_bounds__(256)
void out_kernel(const float* __restrict__ out_w, float* __restrict__ ws, int layer)
{
    const int tid = threadIdx.x;
    const int e = blockIdx.x >> 2, chunk = blockIdx.x & 3;
    const int el = e*3 + layer;
    const int lane = tid & 63, b = tid >> 6;
    const int o = chunk*64 + lane;
    const float* y2 = ws + WS_Y2 + (e*4 + b)*NL*DI;
    const float* sh = ws + WS_SH + (e*4 + b)*NL*DM;
    float* sx = ws + WS_SX + (e*4 + b)*NL*DM;

    const float* w = out_w + (size_t)el*131072 + (size_t)o*512;
    float acc[NL];
    #pragma unroll
    for (int l = 0; l < NL; l++) acc[l] = 0.f;
    for (int d4 = 0; d4 < 128; d4++) {
        float4 wv = *(const float4*)(w + d4*4);
        #pragma unroll
        for (int l = 0; l < NL; l++)
            acc[l] += dot4(wv, *(const float4*)(&y2[l*DI + d4*4]));
    }
    #pragma unroll
    for (int l = 0; l < NL; l++) sx[l*DM + o] = sh[l*DM + o] + acc[l];
}

// ---------------- Kernel 6: gate GEMM + silu.  grid = 8e*4chunks, 256 thr
__global__ __launch_bounds__(256)
void gate_kernel(const float* __restrict__ gate_w, const float* __restrict__ gate_b,
                 float* __restrict__ ws)
{
    const int tid = threadIdx.x;
    const int e = blockIdx.x >> 2, chunk = blockIdx.x & 3;
    const int lane = tid & 63, b = tid >> 6;
    const int o = chunk*64 + lane;
    const float* sx = ws + WS_SX + (e*4 + b)*NL*DM;
    float* gates = ws + WS_GATES;

    const float* w = gate_w + e*65536 + o*256;
    float gb = gate_b[e*256 + o];
    float acc[NL];
    #pragma unroll
    for (int l = 0; l < NL; l++) acc[l] = gb;
    for (int k4 = 0; k4 < 64; k4++) {
        float4 wv = *(const float4*)(w + k4*4);
        #pragma unroll
        for (int l = 0; l < NL; l++)
            acc[l] += dot4(wv, *(const float4*)(&sx[l*DM + k4*4]));
    }
    #pragma unroll
    for (int l = 0; l < NL; l++)
        gates[(e*40 + b*10 + l)*256 + o] = silu(acc[l]);
}

// ---------------- Kernel 7: x_out = x * (1 + gate)
__global__ void scale_kernel(const float* __restrict__ x1, const float* __restrict__ x2,
                             const float* __restrict__ x3, const float* __restrict__ x4,
                             const float* __restrict__ gates, float* __restrict__ out)
{
    int wid  = (blockIdx.x * blockDim.x + threadIdx.x) >> 6;
    int lane = threadIdx.x & 63;
    if (wid >= 40960) return;
    int t = wid / 10240, r = wid % 10240;
    int bt = r >> 8, c = r & 255;
    int lb = (bt & 3)*10 + (bt >> 2);
    const float* src; int hw; size_t obase; int gidx;
    if      (t == 0) { src = x4; hw = 49;   obase = 0;        gidx = (120 + lb)*256 + c; }
    else if (t == 1) { src = x3; hw = 196;  obase = 501760;   gidx = ( 80 + lb)*256 + c; }
    else if (t == 2) { src = x2; hw = 784;  obase = 2508800;  gidx = ( 40 + lb)*256 + c; }
    else             { src = x1; hw = 3136; obase = 10536960; gidx = r; }
    float scale = 1.f + gates[gidx];
    const float* row = src + (size_t)r * hw;
    float* orow = out + obase + (size_t)r * hw;
    if (hw == 49) {
        if (lane < 49) orow[lane] = row[lane] * scale;
    } else {
        int n4 = hw >> 2;
        for (int j = lane; j < n4; j += 64) {
            float4 v = *(const float4*)(row + j*4);
            v.x *= scale; v.y *= scale; v.z *= scale; v.w *= scale;
            *(float4*)(orow + j*4) = v;
        }
    }
}

// ---------------- Kernel 8: ao = audio * (1 + mean(vis gates))
__global__ void ao_kernel(const float* __restrict__ audio, const float* __restrict__ gates,
                          float* __restrict__ out)
{
    int i = blockIdx.x * blockDim.x + threadIdx.x;
    if (i >= 10240) return;
    int bt = i >> 8, c = i & 255;
    int lb = (bt & 3)*10 + (bt >> 2);
    float vg = 0.25f * (gates[(160 + lb)*256 + c] + gates[(200 + lb)*256 + c] +
                        gates[(240 + lb)*256 + c] + gates[(280 + lb)*256 + c]);
    out[42649600 + i] = audio[i] * (1.f + vg);
}

extern "C" void kernel_launch(void* const* d_in, const int* in_sizes, int n_in,
                              void* d_out, int out_size, void* d_ws, size_t ws_size,
                              hipStream_t stream)
{
    const float* x1     = (const float*)d_in[0];
    const float* x2     = (const float*)d_in[1];
    const float* x3     = (const float*)d_in[2];
    const float* x4     = (const float*)d_in[3];
    const float* audio  = (const float*)d_in[4];
    const float* vis_w  = (const float*)d_in[5];
    const float* vis_b  = (const float*)d_in[6];
    const float* ln_g   = (const float*)d_in[7];
    const float* ln_b   = (const float*)d_in[8];
    const float* in_w   = (const float*)d_in[9];
    const float* conv_w = (const float*)d_in[10];
    const float* conv_b = (const float*)d_in[11];
    const float* xp_w   = (const float*)d_in[12];
    const float* dt_w   = (const float*)d_in[13];
    const float* dt_b   = (const float*)d_in[14];
    const float* A_log  = (const float*)d_in[15];
    const float* Dp     = (const float*)d_in[16];
    const float* out_w  = (const float*)d_in[17];
    const float* gate_w = (const float*)d_in[18];
    const float* gate_b = (const float*)d_in[19];

    float* ws  = (float*)d_ws;
    float* out = (float*)d_out;

    pool_kernel<<<dim3(10240), dim3(256), 0, stream>>>(x1, x2, x3, x4, ws + WS_POOLED);
    build_kernel<<<dim3(32), dim3(256), 0, stream>>>(audio, vis_w, vis_b, ws);
    for (int layer = 0; layer < 3; layer++) {
        lnxz_kernel<<<dim3(128), dim3(256), 0, stream>>>(ln_g, ln_b, in_w, ws, layer);
        mid_kernel <<<dim3(32),  dim3(512), 0, stream>>>(conv_w, conv_b, xp_w, dt_w, dt_b,
                                                         A_log, Dp, ws, layer);
        out_kernel <<<dim3(32),  dim3(256), 0, stream>>>(out_w, ws, layer);
    }
    gate_kernel<<<dim3(32), dim3(256), 0, stream>>>(gate_w, gate_b, ws);
    scale_kernel<<<dim3(10240), dim3(256), 0, stream>>>(x1, x2, x3, x4, ws + WS_GATES, out);
    ao_kernel<<<dim3(10), dim3(1024), 0, stream>>>(audio, ws + WS_GATES, out);
}